// Round 4
// baseline (411.670 us; speedup 1.0000x reference)
//
#include <hip/hip_runtime.h>

// Problem constants (fixed by reference): B=4, S=2048, DIN=4096, DOUT=4096
#define GM 8192   // M = B*S
#define GN 4096   // N = DOUT
#define GK 4096   // K = DIN

#define BM 256
#define BN 256
#define BK 64             // bytes of K per K-tile (i8)
#define NTILE (GK / BK)   // 64 K-tiles
#define SLOT 32768        // one K-tile: A 16 KiB (2 halves) + B 16 KiB

using int4v = __attribute__((ext_vector_type(4))) int;

// ---------------- fused quantization ----------------
__global__ __launch_bounds__(256) void quant_xw_k(
    const float4* __restrict__ x, unsigned int* __restrict__ xq,
    const float4* __restrict__ w, unsigned int* __restrict__ wq,
    const float* __restrict__ wscale, const float* __restrict__ iscale,
    int n4x, int n4tot) {
    const float xs = *iscale;
    const int stride = gridDim.x * blockDim.x;
    for (int i = blockIdx.x * blockDim.x + threadIdx.x; i < n4tot; i += stride) {
        if (i < n4x) {
            float4 v = x[i];
            int q0 = (int)(v.x * xs);
            int q1 = (int)(v.y * xs);
            int q2 = (int)(v.z * xs);
            int q3 = (int)(v.w * xs);
            xq[i] = (unsigned int)(q0 & 0xff)
                  | ((unsigned int)(q1 & 0xff) << 8)
                  | ((unsigned int)(q2 & 0xff) << 16)
                  | ((unsigned int)(q3 & 0xff) << 24);
        } else {
            int j = i - n4x;
            float s = wscale[j >> 10];
            float4 v = w[j];
            int q0 = (int)rintf(v.x * s);
            int q1 = (int)rintf(v.y * s);
            int q2 = (int)rintf(v.z * s);
            int q3 = (int)rintf(v.w * s);
            wq[j] = (unsigned int)(q0 & 0xff)
                  | ((unsigned int)(q1 & 0xff) << 8)
                  | ((unsigned int)(q2 & 0xff) << 16)
                  | ((unsigned int)(q3 & 0xff) << 24);
        }
    }
}

// ---------------- int8 GEMM: m201-style 8-phase schedule ----------------
// 256x256 tile, 512 thr, 8 waves 2Mx4N (wave tile 128x64, acc[8][4]).
// 2 LDS slots of 32 KiB (tile t even -> slot0, odd -> slot1).
// Iteration = 2 K-tiles = 8 phases; phase = {<=6 ds_read | <=1 stage group;
//   barrier; lgkmcnt(0)+sched_barrier; setprio(1); 8 MFMA; setprio(0);
//   barrier}.  vmcnt(0) only at phases 4/8, where in-flight GLLs are 3
//   phases (~1200 cyc) old -> near-free.  Ledger:
//   - STAGE(kA->slot1) at phase 1: slot1's readers all passed their
//     lgkmcnt(0) + PH(3)-barrier in the previous half -> safe overwrite.
//   - reads(slot1) at phase 5: its GLLs retired by phase-4 vmcnt(0)+barrier.
//   - symmetric for slot0 at phases 5 / next-iter 1.
// Swizzle (verified, SQ_LDS_BANK_CONFLICT==0 in R1-R3): stored slot s of
// row r holds chunk s ^ ((r>>1)&3); GLL writes linearly so the *source*
// chunk is permuted: kc = (tid&3)^((tid>>3)&3); reads use
// pos = ((lane>>4)^((lane>>1)&3))*16.
__global__ __launch_bounds__(512, 2) void qlinear_gemm_i8(
    const signed char* __restrict__ Aq,
    const signed char* __restrict__ Bq,
    const float* __restrict__ bias,
    const float* __restrict__ wscale,
    const float* __restrict__ iscale,
    float* __restrict__ C) {
    __shared__ signed char smem[2 * SLOT];   // 64 KiB

    const int tid  = threadIdx.x;
    const int wave = tid >> 6;
    const int lane = tid & 63;
    const int m0 = blockIdx.x * BM;
    const int n0 = blockIdx.y * BN;
    const int wm = (wave >> 2) * 128;    // {0,128}
    const int wn = (wave & 3) * 64;      // {0,64,128,192}

    int4v acc[8][4];
#pragma unroll
    for (int i = 0; i < 8; ++i)
#pragma unroll
        for (int j = 0; j < 4; ++j)
            acc[i][j] = int4v{0, 0, 0, 0};

    // --- staging: 512 threads cover one 128-row half (8 KiB) per GLL
    const int kc = ((tid & 3) ^ ((tid >> 3) & 3)) * 16;   // swizzled src chunk
    const signed char* gA  = Aq + (size_t)(m0 + (tid >> 2)) * GK + kc;
    const signed char* gA2 = gA + (size_t)128 * GK;
    const signed char* gB  = Bq + (size_t)(n0 + (tid >> 2)) * GK + kc;
    const signed char* gB2 = gB + (size_t)128 * GK;
    const int dst = tid * 16;                             // linear LDS dest

    // --- LDS fragment read offsets (within one slot)
    const int pos = (((lane >> 4) ^ ((lane >> 1) & 3))) * 16;
    const int fAo = (wm + (lane & 15)) * 64 + pos;            // + mi*1024
    const int fBo = 16384 + (wn + (lane & 15)) * 64 + pos;    // + ni*1024

#define GLL16(g, l)                                                     \
    __builtin_amdgcn_global_load_lds(                                   \
        (__attribute__((address_space(1))) void*)(void*)(g),            \
        (__attribute__((address_space(3))) void*)(void*)(l), 16, 0, 0)

#define STAGE(kb, soff)                                                 \
    do {                                                                \
        GLL16(gA  + (kb), smem + (soff) + dst);                         \
        GLL16(gA2 + (kb), smem + (soff) + 8192 + dst);                  \
        GLL16(gB  + (kb), smem + (soff) + 16384 + dst);                 \
        GLL16(gB2 + (kb), smem + (soff) + 24576 + dst);                 \
    } while (0)

#define DSR(off) (*(const int4v*)(smem + (off)))
#define MFMA(A, B, Cc) __builtin_amdgcn_mfma_i32_16x16x64_i8(A, B, Cc, 0, 0, 0)

// one phase: rendezvous, drain LDS reads, 8 independent MFMAs
#define PH(q)                                                           \
    __builtin_amdgcn_s_barrier();                                       \
    asm volatile("s_waitcnt lgkmcnt(0)" ::: "memory");                  \
    __builtin_amdgcn_sched_barrier(0);                                  \
    __builtin_amdgcn_s_setprio(1);                                      \
    acc[2*(q)  ][0] = MFMA(pa0, bfr0, acc[2*(q)  ][0]);                 \
    acc[2*(q)+1][0] = MFMA(pa1, bfr0, acc[2*(q)+1][0]);                 \
    acc[2*(q)  ][1] = MFMA(pa0, bfr1, acc[2*(q)  ][1]);                 \
    acc[2*(q)+1][1] = MFMA(pa1, bfr1, acc[2*(q)+1][1]);                 \
    acc[2*(q)  ][2] = MFMA(pa0, bfr2, acc[2*(q)  ][2]);                 \
    acc[2*(q)+1][2] = MFMA(pa1, bfr2, acc[2*(q)+1][2]);                 \
    acc[2*(q)  ][3] = MFMA(pa0, bfr3, acc[2*(q)  ][3]);                 \
    acc[2*(q)+1][3] = MFMA(pa1, bfr3, acc[2*(q)+1][3]);                 \
    __builtin_amdgcn_s_setprio(0);                                      \
    __builtin_amdgcn_s_barrier();

// 4 phases covering one K-tile from slot at byte offset SOFF.
// STAGE_CODE issues this half's prefetch at phase q0; vmcnt(0) before the
// 4th phase retires GLLs issued 3 phases earlier.
#define HALF(SOFF, STAGE_CODE)                                          \
    do {                                                                \
        STAGE_CODE;                                                     \
        bfr0 = DSR((SOFF) + fBo);                                       \
        bfr1 = DSR((SOFF) + fBo + 1024);                                \
        bfr2 = DSR((SOFF) + fBo + 2048);                                \
        bfr3 = DSR((SOFF) + fBo + 3072);                                \
        pa0  = DSR((SOFF) + fAo);                                       \
        pa1  = DSR((SOFF) + fAo + 1024);                                \
        PH(0)                                                           \
        pa0 = DSR((SOFF) + fAo + 2048);                                 \
        pa1 = DSR((SOFF) + fAo + 3072);                                 \
        PH(1)                                                           \
        pa0 = DSR((SOFF) + fAo + 4096);                                 \
        pa1 = DSR((SOFF) + fAo + 5120);                                 \
        PH(2)                                                           \
        pa0 = DSR((SOFF) + fAo + 6144);                                 \
        pa1 = DSR((SOFF) + fAo + 7168);                                 \
        asm volatile("s_waitcnt vmcnt(0)" ::: "memory");                \
        PH(3)                                                           \
    } while (0)

    // --- prologue: stage tile0 -> slot0; rendezvous.
    STAGE(0, 0);
    asm volatile("s_waitcnt vmcnt(0)" ::: "memory");
    __builtin_amdgcn_s_barrier();
    __builtin_amdgcn_sched_barrier(0);

    int4v bfr0, bfr1, bfr2, bfr3, pa0, pa1;
    int kA = BK;        // k-byte of odd tile (2it+1) staged into slot1 @ P1
    int kB = 2 * BK;    // k-byte of even tile (2it+2) staged into slot0 @ P5
    for (int it = 0; it < NTILE / 2; ++it) {
        HALF(0,    { STAGE(kA, SLOT); kA += 2 * BK; });
        HALF(SLOT, { if (kB < GK) { STAGE(kB, 0); kB += 2 * BK; } });
    }

    // --- epilogue: C/D layout col=lane&15, row=(lane>>4)*4+reg
    const float isc = *iscale;
#pragma unroll
    for (int ni = 0; ni < 4; ++ni) {
        const int col = n0 + wn + ni * 16 + (lane & 15);
        const float bs_ = bias[col];
        const float inv = 1.0f / (wscale[col] * isc);
#pragma unroll
        for (int mi = 0; mi < 8; ++mi) {
            const int row0 = m0 + wm + mi * 16 + (lane >> 4) * 4;
#pragma unroll
            for (int r = 0; r < 4; ++r) {
                C[(size_t)(row0 + r) * GN + col] =
                    ((float)acc[mi][ni][r] + bs_) * inv;
            }
        }
    }
#undef HALF
#undef PH
#undef DSR
#undef MFMA
#undef STAGE
#undef GLL16
}

extern "C" void kernel_launch(void* const* d_in, const int* in_sizes, int n_in,
                              void* d_out, int out_size, void* d_ws, size_t ws_size,
                              hipStream_t stream) {
    const float* x      = (const float*)d_in[0];  // (4,2048,4096)
    const float* w      = (const float*)d_in[1];  // (4096,4096)
    const float* bias   = (const float*)d_in[2];  // (4096,)
    const float* wscale = (const float*)d_in[3];  // (4096,)
    const float* iscale = (const float*)d_in[4];  // (1,)
    float* out = (float*)d_out;

    signed char* xq = (signed char*)d_ws;                       // 32 MiB
    signed char* wq = xq + (size_t)GM * GK;                     // 16 MiB

    const int n4x = GM * GK / 4;
    const int n4w = GN * GK / 4;
    quant_xw_k<<<3072, 256, 0, stream>>>((const float4*)x, (unsigned int*)xq,
                                         (const float4*)w, (unsigned int*)wq,
                                         wscale, iscale, n4x, n4x + n4w);

    dim3 grid(GM / BM, GN / BN);   // 32 x 16 = 512 blocks of 512 threads
    qlinear_gemm_i8<<<grid, 512, 0, stream>>>(xq, wq, bias, wscale, iscale, out);
}